// Round 2
// baseline (469.799 us; speedup 1.0000x reference)
//
#include <hip/hip_runtime.h>
#include <stdint.h>
#include <math.h>

// Problem constants
#define NTOK 8192   // B*S tokens
#define FIN  4096
#define FOUT 4096
#define PP   512
#define QIN  8
#define QOUT 8
#define NFREQ 257   // P/2+1

// ---------------------------------------------------------------------------
// complex helpers
// ---------------------------------------------------------------------------
__device__ __forceinline__ float2 cadd(float2 a, float2 b) { return make_float2(a.x + b.x, a.y + b.y); }
__device__ __forceinline__ float2 csub(float2 a, float2 b) { return make_float2(a.x - b.x, a.y - b.y); }

// a * t, conjugating t when INV (t = forward twiddle, W = e^{-2pi i/512})
template<int INV>
__device__ __forceinline__ float2 twmul(float2 a, float2 t) {
    const float ty = INV ? -t.y : t.y;
    return make_float2(a.x * t.x - a.y * ty, a.x * ty + a.y * t.x);
}

// ---------------------------------------------------------------------------
// In-register 8-point DFT over the register index.
// ---------------------------------------------------------------------------
template<int INV>
__device__ __forceinline__ void dft8(float2 z[8]) {
    const float S = 0.70710678118654752f;
    float2 a0 = cadd(z[0], z[4]), a4 = csub(z[0], z[4]);
    float2 a1 = cadd(z[1], z[5]), a5 = csub(z[1], z[5]);
    float2 a2 = cadd(z[2], z[6]), a6 = csub(z[2], z[6]);
    float2 a3 = cadd(z[3], z[7]), a7 = csub(z[3], z[7]);
    float2 b0 = cadd(a0, a2), b2 = csub(a0, a2);
    float2 b1 = cadd(a1, a3), b3 = csub(a1, a3);
    z[0] = cadd(b0, b1);
    z[4] = csub(b0, b1);
    float2 r3 = INV ? make_float2(-b3.y, b3.x) : make_float2(b3.y, -b3.x);
    z[2] = cadd(b2, r3);
    z[6] = csub(b2, r3);
    float2 c0 = a4;
    float2 c1 = INV ? make_float2(S * (a5.x - a5.y), S * (a5.x + a5.y))
                    : make_float2(S * (a5.x + a5.y), S * (a5.y - a5.x));
    float2 c2 = INV ? make_float2(-a6.y, a6.x) : make_float2(a6.y, -a6.x);
    float2 c3 = INV ? make_float2(-S * (a7.x + a7.y), S * (a7.x - a7.y))
                    : make_float2(S * (a7.y - a7.x), -S * (a7.x + a7.y));
    float2 d0 = cadd(c0, c2), d2 = csub(c0, c2);
    float2 d1 = cadd(c1, c3), d3 = csub(c1, c3);
    z[1] = cadd(d0, d1);
    z[5] = csub(d0, d1);
    float2 r7 = INV ? make_float2(-d3.y, d3.x) : make_float2(d3.y, -d3.x);
    z[3] = cadd(d2, r7);
    z[7] = csub(d2, r7);
}

// XOR-swizzled transpose-scratch address: logical (row, col) in an 8x64 tile
// packed into 512 float2 slots.  Bijective; all four access patterns below
// land 4 lanes per bank-pair (b64 wave minimum = conflict-free).
#define SW(row, col) (((row) << 6) + ((col) ^ (((row) & 3) << 2)))

// ---------------------------------------------------------------------------
// Per-wave 512-point FFT, four-step radix-8^3 (natural order in / out).
//   n = 64*n2 + 8*n1 + n0 ; k = k0 + 8*k1 + 64*k2 ; lane = 8h + w
// TAt[k*64+lane] = W512^{8*h*k} ; TBt[k*64+lane] = W512^{(w*(h+8k))&511}
// Mt = this wave's 512-slot plane (aliases spectra storage; same-wave DS
// ordering makes the aliasing safe).
// ---------------------------------------------------------------------------
template<int INV>
__device__ __forceinline__ void fft512(float2 z[8], float2* Mt,
                                       const float2* TAt, const float2* TBt,
                                       const int lane, const int h, const int w) {
    dft8<INV>(z);                                   // over n2 -> k0
#pragma unroll
    for (int k = 1; k < 8; ++k)
        z[k] = twmul<INV>(z[k], TAt[k * 64 + lane]);
#pragma unroll
    for (int k = 0; k < 8; ++k) Mt[SW(k, lane)] = z[k];          // T1 write
#pragma unroll
    for (int k = 0; k < 8; ++k) z[k] = Mt[SW(h, 8 * k + w)];     // T1 read
    dft8<INV>(z);                                   // over n1 -> k1
#pragma unroll
    for (int k = 0; k < 8; ++k)
        z[k] = twmul<INV>(z[k], TBt[k * 64 + lane]);
#pragma unroll
    for (int k = 0; k < 8; ++k) Mt[SW(k, 8 * w + h)] = z[k];     // T2 write
#pragma unroll
    for (int k = 0; k < 8; ++k) z[k] = Mt[SW(h, 8 * k + w)];     // T2 read
    dft8<INV>(z);                                   // over n0 -> k2
}

// ---------------------------------------------------------------------------
// Cheap exact-enough GELU: A&S 7.1.26 erf (|eps| <= 1.5e-7), rcp + exp + 5 fma.
// ---------------------------------------------------------------------------
__device__ __forceinline__ float gelu_f(float v) {
    const float a = fabsf(v) * 0.70710678118654752f;
    const float t = __builtin_amdgcn_rcpf(fmaf(0.3275911f, a, 1.0f));
    float p = fmaf(1.061405429f, t, -1.453152027f);
    p = fmaf(p, t, 1.421413741f);
    p = fmaf(p, t, -0.284496736f);
    p = fmaf(p, t, 0.254829592f);
    p = p * t;
    const float e = __expf(-a * a);
    float erfa = fmaf(-p, e, 1.0f);         // erf(|v|/sqrt2)
    erfa = copysignf(erfa, v);
    return 0.5f * v * (1.0f + erfa);
}

// ---------------------------------------------------------------------------
// wf_build: Wf4[(o*4+i2)*257 + f] = float4{ Wf[o][2*i2][f], Wf[o][2*i2+1][f] }
// (pairs of adjacent input blocks packed so fft_conv loads dwordx4).
// Wf = (1/512) * rfft(w[o][i]).  Block blk = o*8+i computes one (o,i) row
// and writes its float2 half-slot.  libm sincos kept here (64 blocks only).
// ---------------------------------------------------------------------------
__global__ __launch_bounds__(256) void wf_build(const float* __restrict__ w,
                                                float4* __restrict__ Wf4) {
    __shared__ float  sw[512];
    __shared__ float2 tb[512];          // tb[k] = W^k = (cos, -sin)(2pi k/512)
    __shared__ float2 red[4][64];
    const int blk = blockIdx.x;         // o*8 + i
    const float* wrow = w + (size_t)blk * 512;
    const int t   = threadIdx.x;
    const int fi  = t & 63;
    const int seg = t >> 6;
    sw[t]       = wrow[t];
    sw[t + 256] = wrow[t + 256];
    const float th = -6.283185307179586f / 512.0f;
    {
        float a0 = th * (float)t, a1 = th * (float)(t + 256);
        tb[t]       = make_float2(cosf(a0), sinf(a0));
        tb[t + 256] = make_float2(cosf(a1), sinf(a1));
    }
    __syncthreads();
    const int o = blk >> 3, i = blk & 7;
    float2* dst_base = (float2*)Wf4 + (i & 1);      // float4 slot = 2 float2
    for (int g = 0; g < 5; ++g) {
        const int f = (g < 4) ? (g * 64 + fi) : 256;
        float re = 0.f, im = 0.f;
        int idx = (f * (seg * 128)) & 511;
        for (int n = 0; n < 128; ++n) {
            const float2 e = tb[idx];
            const float  v = sw[seg * 128 + n];
            re += v * e.x;
            im += v * e.y;
            idx = (idx + f) & 511;
        }
        red[seg][fi] = make_float2(re, im);
        __syncthreads();
        if (seg == 0) {
            float2 r0 = red[0][fi], r1 = red[1][fi], r2 = red[2][fi], r3 = red[3][fi];
            float rre = (r0.x + r1.x) + (r2.x + r3.x);
            float rim = (r0.y + r1.y) + (r2.y + r3.y);
            if (g < 4 || fi == 0)
                dst_base[((size_t)(o * 4 + (i >> 1)) * 257 + f) * 2] =
                    make_float2(rre * (1.f / 512.f), rim * (1.f / 512.f));
        }
        __syncthreads();
    }
}

// ---------------------------------------------------------------------------
// fft_conv: one block (256 thr, 4 waves) per token.  Wave c handles packed
// complex sequence Z_c = xs[2c] + i*xs[2c+1].
// LDS (float2 units), 3072 total = 24576 B:
//   ZS  [0,2048)     : c*512 + n  — spectra; ALSO per-wave fft512 scratch and
//                      einsum output (in-place: pair {f,512-f} is private to
//                      the thread handling f)
//   TAt [2048,2560)  : k*64+lane twiddles, stage A
//   TBt [2560,3072)  : k*64+lane twiddles, stage B
// ---------------------------------------------------------------------------
__global__ __launch_bounds__(256, 5) void fft_conv(const float* __restrict__ x,
                                                   const int* __restrict__ sign_bits,
                                                   const float4* __restrict__ Wf4,
                                                   const float* __restrict__ bias,
                                                   float* __restrict__ out) {
    __shared__ float2 LB[3072];

    const int tid  = threadIdx.x;
    const int wave = tid >> 6;
    const int lane = tid & 63;
    const int h = lane >> 3, w = lane & 7;
    const float* xin  = x   + (size_t)blockIdx.x * FIN;
    float*       yout = out + (size_t)blockIdx.x * FOUT;

    // ---- per-lane twiddle tables (HW sincos, no libm, no per-stage idx math)
    for (int j = tid; j < 1024; j += 256) {
        const int k  = (j >> 6) & 7;
        const int l  = j & 63;
        const int hh = l >> 3, ww = l & 7;
        const int e  = (j < 512) ? ((8 * hh * k) & 511)
                                 : ((ww * (hh + 8 * k)) & 511);
        float sn, cs;
        __sincosf((-6.283185307179586f / 512.0f) * (float)e, &sn, &cs);
        LB[2048 + j] = make_float2(cs, sn);
    }
    __syncthreads();

    const float2* TAt = &LB[2048];
    const float2* TBt = &LB[2560];
    float2* Mt = &LB[wave * 512];        // wave-private plane (scratch+spectra)

    // ---- pack x*sign into registers (reg k = element 64k+lane) ----
    float2 z[8];
    {
        const float* xre = xin + (2 * wave) * 512;
        const float* xim = xin + (2 * wave + 1) * 512;
        const int*   sre = sign_bits + (2 * wave) * 512;
        const int*   sim = sign_bits + (2 * wave + 1) * 512;
#pragma unroll
        for (int k = 0; k < 8; ++k) {
            const int p = 64 * k + lane;
            float a = xre[p], b = xim[p];
            unsigned sa = (unsigned)sre[p] << 31;
            unsigned sb = (unsigned)sim[p] << 31;
            z[k].x = __uint_as_float(__float_as_uint(a) ^ sa);
            z[k].y = __uint_as_float(__float_as_uint(b) ^ sb);
        }
    }

    // ---- forward FFT (wave-private; scratch aliases own plane) ----
    fft512<0>(z, Mt, TAt, TBt, lane, h, w);

#pragma unroll
    for (int k = 0; k < 8; ++k) Mt[64 * k + lane] = z[k];    // spectra, natural
    __syncthreads();

    // ---- spectral einsum, in place (thread f owns slots {f, 512-f}) ----
    for (int f = tid; f <= 256; f += 256) {     // thread 0 also does f=256
        const int fm = (512 - f) & 511;
        float2 Xf[8];
#pragma unroll
        for (int c = 0; c < 4; ++c) {
            const float2 zp = LB[c * 512 + f];
            const float2 zm = LB[c * 512 + fm];
            Xf[2 * c]     = make_float2(0.5f * (zp.x + zm.x), 0.5f * (zp.y - zm.y));
            Xf[2 * c + 1] = make_float2(0.5f * (zp.y + zm.y), -0.5f * (zp.x - zm.x));
        }
        const float4* wf = Wf4 + f;
        float2 Y[8];
#pragma unroll
        for (int o = 0; o < 8; ++o) {
            float re = 0.f, im = 0.f;
#pragma unroll
            for (int i2 = 0; i2 < 4; ++i2) {
                const float4 wv = wf[(o * 4 + i2) * 257];    // coalesced dwordx4
                const float2 x0 = Xf[2 * i2], x1 = Xf[2 * i2 + 1];
                re += x0.x * wv.x - x0.y * wv.y;
                re += x1.x * wv.z - x1.y * wv.w;
                im += x0.x * wv.y + x0.y * wv.x;
                im += x1.x * wv.w + x1.y * wv.z;
            }
            Y[o] = make_float2(re, im);
        }
#pragma unroll
        for (int c = 0; c < 4; ++c) {
            const float2 y0 = Y[2 * c], y1 = Y[2 * c + 1];
            LB[c * 512 + f] = make_float2(y0.x - y1.y, y0.y + y1.x);
            if (f != 0 && f != 256)
                LB[c * 512 + 512 - f] = make_float2(y0.x + y1.y, y1.x - y0.y);
        }
    }
    __syncthreads();

    // ---- inverse FFT (reads own plane, then scratch clobbers it) ----
#pragma unroll
    for (int k = 0; k < 8; ++k) z[k] = Mt[64 * k + lane];

    fft512<1>(z, Mt, TAt, TBt, lane, h, w);

    // ---- epilogue: bias + GELU (A&S erf), coalesced stores ----
    {
        const float* bre = bias + (2 * wave) * 512;
        const float* bim = bias + (2 * wave + 1) * 512;
        float* yre = yout + (2 * wave) * 512;
        float* yim = yout + (2 * wave + 1) * 512;
#pragma unroll
        for (int k = 0; k < 8; ++k) {
            const int p = 64 * k + lane;
            yre[p] = gelu_f(z[k].x + bre[p]);
            yim[p] = gelu_f(z[k].y + bim[p]);
        }
    }
}

extern "C" void kernel_launch(void* const* d_in, const int* in_sizes, int n_in,
                              void* d_out, int out_size, void* d_ws, size_t ws_size,
                              hipStream_t stream) {
    const float* x        = (const float*)d_in[0];   // [B,S,F_IN] fp32
    const float* w        = (const float*)d_in[1];   // [QOUT,QIN,P] fp32
    const float* bias     = (const float*)d_in[2];   // [F_OUT] fp32
    const int*  sign_bits = (const int*)d_in[3];     // [F_IN] int32
    float* out = (float*)d_out;                      // [B,S,F_OUT] fp32

    float4* Wf4 = (float4*)d_ws;                     // [32][257] float4 = 131.6 KB

    wf_build<<<QOUT * QIN, 256, 0, stream>>>(w, Wf4);
    fft_conv<<<NTOK, 256, 0, stream>>>(x, sign_bits, Wf4, bias, out);
}

// Round 3
// 370.132 us; speedup vs baseline: 1.2693x; 1.2693x over previous
//
#include <hip/hip_runtime.h>
#include <stdint.h>
#include <math.h>

// Problem constants
#define NTOK 8192   // B*S tokens
#define FIN  4096
#define FOUT 4096
#define PP   512
#define QIN  8
#define QOUT 8
#define NFREQ 257   // P/2+1

// ---------------------------------------------------------------------------
// complex helpers
// ---------------------------------------------------------------------------
__device__ __forceinline__ float2 cadd(float2 a, float2 b) { return make_float2(a.x + b.x, a.y + b.y); }
__device__ __forceinline__ float2 csub(float2 a, float2 b) { return make_float2(a.x - b.x, a.y - b.y); }

// a * t, conjugating t when INV (t = forward twiddle, W = e^{-2pi i/512})
template<int INV>
__device__ __forceinline__ float2 twmul(float2 a, float2 t) {
    const float ty = INV ? -t.y : t.y;
    return make_float2(a.x * t.x - a.y * ty, a.x * ty + a.y * t.x);
}

// ---------------------------------------------------------------------------
// In-register 8-point DFT over the register index.
// ---------------------------------------------------------------------------
template<int INV>
__device__ __forceinline__ void dft8(float2 z[8]) {
    const float S = 0.70710678118654752f;
    float2 a0 = cadd(z[0], z[4]), a4 = csub(z[0], z[4]);
    float2 a1 = cadd(z[1], z[5]), a5 = csub(z[1], z[5]);
    float2 a2 = cadd(z[2], z[6]), a6 = csub(z[2], z[6]);
    float2 a3 = cadd(z[3], z[7]), a7 = csub(z[3], z[7]);
    float2 b0 = cadd(a0, a2), b2 = csub(a0, a2);
    float2 b1 = cadd(a1, a3), b3 = csub(a1, a3);
    z[0] = cadd(b0, b1);
    z[4] = csub(b0, b1);
    float2 r3 = INV ? make_float2(-b3.y, b3.x) : make_float2(b3.y, -b3.x);
    z[2] = cadd(b2, r3);
    z[6] = csub(b2, r3);
    float2 c0 = a4;
    float2 c1 = INV ? make_float2(S * (a5.x - a5.y), S * (a5.x + a5.y))
                    : make_float2(S * (a5.x + a5.y), S * (a5.y - a5.x));
    float2 c2 = INV ? make_float2(-a6.y, a6.x) : make_float2(a6.y, -a6.x);
    float2 c3 = INV ? make_float2(-S * (a7.x + a7.y), S * (a7.x - a7.y))
                    : make_float2(S * (a7.y - a7.x), -S * (a7.x + a7.y));
    float2 d0 = cadd(c0, c2), d2 = csub(c0, c2);
    float2 d1 = cadd(c1, c3), d3 = csub(c1, c3);
    z[1] = cadd(d0, d1);
    z[5] = csub(d0, d1);
    float2 r7 = INV ? make_float2(-d3.y, d3.x) : make_float2(d3.y, -d3.x);
    z[3] = cadd(d2, r7);
    z[7] = csub(d2, r7);
}

// XOR-swizzled transpose-scratch address: logical (row, col) in an 8x64 tile
// packed into 512 float2 slots.  Bijective; all four access patterns below
// land 4 lanes per bank-pair (b64 wave minimum = conflict-free).
#define SW(row, col) (((row) << 6) + ((col) ^ (((row) & 3) << 2)))

// ---------------------------------------------------------------------------
// Per-wave 512-point FFT, four-step radix-8^3 (natural order in / out).
//   n = 64*n2 + 8*n1 + n0 ; k = k0 + 8*k1 + 64*k2 ; lane = 8h + w
// TAt[k*64+lane] = W512^{8*h*k} ; TBt[k*64+lane] = W512^{(w*(h+8k))&511}
// Mt = this wave's 512-slot plane (aliases spectra storage; same-wave DS
// ordering makes the aliasing safe).
// ---------------------------------------------------------------------------
template<int INV>
__device__ __forceinline__ void fft512(float2 z[8], float2* Mt,
                                       const float2* TAt, const float2* TBt,
                                       const int lane, const int h, const int w) {
    dft8<INV>(z);                                   // over n2 -> k0
#pragma unroll
    for (int k = 1; k < 8; ++k)
        z[k] = twmul<INV>(z[k], TAt[k * 64 + lane]);
#pragma unroll
    for (int k = 0; k < 8; ++k) Mt[SW(k, lane)] = z[k];          // T1 write
#pragma unroll
    for (int k = 0; k < 8; ++k) z[k] = Mt[SW(h, 8 * k + w)];     // T1 read
    dft8<INV>(z);                                   // over n1 -> k1
#pragma unroll
    for (int k = 0; k < 8; ++k)
        z[k] = twmul<INV>(z[k], TBt[k * 64 + lane]);
#pragma unroll
    for (int k = 0; k < 8; ++k) Mt[SW(k, 8 * w + h)] = z[k];     // T2 write
#pragma unroll
    for (int k = 0; k < 8; ++k) z[k] = Mt[SW(h, 8 * k + w)];     // T2 read
    dft8<INV>(z);                                   // over n0 -> k2
}

// ---------------------------------------------------------------------------
// Cheap exact-enough GELU: A&S 7.1.26 erf (|eps| <= 1.5e-7), rcp + exp + 5 fma.
// ---------------------------------------------------------------------------
__device__ __forceinline__ float gelu_f(float v) {
    const float a = fabsf(v) * 0.70710678118654752f;
    const float t = __builtin_amdgcn_rcpf(fmaf(0.3275911f, a, 1.0f));
    float p = fmaf(1.061405429f, t, -1.453152027f);
    p = fmaf(p, t, 1.421413741f);
    p = fmaf(p, t, -0.284496736f);
    p = fmaf(p, t, 0.254829592f);
    p = p * t;
    const float e = __expf(-a * a);
    float erfa = fmaf(-p, e, 1.0f);         // erf(|v|/sqrt2)
    erfa = copysignf(erfa, v);
    return 0.5f * v * (1.0f + erfa);
}

// ---------------------------------------------------------------------------
// wf_build: Wf4[(o*4+i2)*257 + f] = float4{ Wf[o][2*i2][f], Wf[o][2*i2+1][f] }
// (pairs of adjacent input blocks packed so fft_conv loads dwordx4).
// Wf = (1/512) * rfft(w[o][i]).  Block blk = o*8+i computes one (o,i) row
// and writes its float2 half-slot.  libm sincos kept here (64 blocks only).
// ---------------------------------------------------------------------------
__global__ __launch_bounds__(256) void wf_build(const float* __restrict__ w,
                                                float4* __restrict__ Wf4) {
    __shared__ float  sw[512];
    __shared__ float2 tb[512];          // tb[k] = W^k = (cos, -sin)(2pi k/512)
    __shared__ float2 red[4][64];
    const int blk = blockIdx.x;         // o*8 + i
    const float* wrow = w + (size_t)blk * 512;
    const int t   = threadIdx.x;
    const int fi  = t & 63;
    const int seg = t >> 6;
    sw[t]       = wrow[t];
    sw[t + 256] = wrow[t + 256];
    const float th = -6.283185307179586f / 512.0f;
    {
        float a0 = th * (float)t, a1 = th * (float)(t + 256);
        tb[t]       = make_float2(cosf(a0), sinf(a0));
        tb[t + 256] = make_float2(cosf(a1), sinf(a1));
    }
    __syncthreads();
    const int o = blk >> 3, i = blk & 7;
    float2* dst_base = (float2*)Wf4 + (i & 1);      // float4 slot = 2 float2
    for (int g = 0; g < 5; ++g) {
        const int f = (g < 4) ? (g * 64 + fi) : 256;
        float re = 0.f, im = 0.f;
        int idx = (f * (seg * 128)) & 511;
        for (int n = 0; n < 128; ++n) {
            const float2 e = tb[idx];
            const float  v = sw[seg * 128 + n];
            re += v * e.x;
            im += v * e.y;
            idx = (idx + f) & 511;
        }
        red[seg][fi] = make_float2(re, im);
        __syncthreads();
        if (seg == 0) {
            float2 r0 = red[0][fi], r1 = red[1][fi], r2 = red[2][fi], r3 = red[3][fi];
            float rre = (r0.x + r1.x) + (r2.x + r3.x);
            float rim = (r0.y + r1.y) + (r2.y + r3.y);
            if (g < 4 || fi == 0)
                dst_base[((size_t)(o * 4 + (i >> 1)) * 257 + f) * 2] =
                    make_float2(rre * (1.f / 512.f), rim * (1.f / 512.f));
        }
        __syncthreads();
    }
}

// ---------------------------------------------------------------------------
// fft_conv: one block (256 thr, 4 waves) per token.  Wave c handles packed
// complex sequence Z_c = xs[2c] + i*xs[2c+1].
// LDS (float2 units), 3072 total = 24576 B:
//   ZS  [0,2048)     : c*512 + n  — spectra; ALSO per-wave fft512 scratch and
//                      einsum output (in-place: slot s is read AND written by
//                      exactly one thread -> race-free across waves)
//   TAt [2048,2560)  : k*64+lane twiddles, stage A
//   TBt [2560,3072)  : k*64+lane twiddles, stage B
// __launch_bounds__(256, 4): VGPR cap 128.  (256,5) capped at 48 VGPR and
// spilled catastrophically (R2: FETCH 66->336 MB, WRITE 131->679 MB).
// ---------------------------------------------------------------------------
__global__ __launch_bounds__(256, 4) void fft_conv(const float* __restrict__ x,
                                                   const int* __restrict__ sign_bits,
                                                   const float4* __restrict__ Wf4,
                                                   const float* __restrict__ bias,
                                                   float* __restrict__ out) {
    __shared__ float2 LB[3072];

    const int tid  = threadIdx.x;
    const int wave = tid >> 6;
    const int lane = tid & 63;
    const int h = lane >> 3, w = lane & 7;
    const float* xin  = x   + (size_t)blockIdx.x * FIN;
    float*       yout = out + (size_t)blockIdx.x * FOUT;

    // ---- per-lane twiddle tables (HW sincos, no libm, no per-stage idx math)
    for (int j = tid; j < 1024; j += 256) {
        const int k  = (j >> 6) & 7;
        const int l  = j & 63;
        const int hh = l >> 3, ww = l & 7;
        const int e  = (j < 512) ? ((8 * hh * k) & 511)
                                 : ((ww * (hh + 8 * k)) & 511);
        float sn, cs;
        __sincosf((-6.283185307179586f / 512.0f) * (float)e, &sn, &cs);
        LB[2048 + j] = make_float2(cs, sn);
    }
    __syncthreads();

    const float2* TAt = &LB[2048];
    const float2* TBt = &LB[2560];
    float2* Mt = &LB[wave * 512];        // wave-private plane (scratch+spectra)

    // ---- pack x*sign into registers (reg k = element 64k+lane) ----
    float2 z[8];
    {
        const float* xre = xin + (2 * wave) * 512;
        const float* xim = xin + (2 * wave + 1) * 512;
        const int*   sre = sign_bits + (2 * wave) * 512;
        const int*   sim = sign_bits + (2 * wave + 1) * 512;
#pragma unroll
        for (int k = 0; k < 8; ++k) {
            const int p = 64 * k + lane;
            float a = xre[p], b = xim[p];
            unsigned sa = (unsigned)sre[p] << 31;
            unsigned sb = (unsigned)sim[p] << 31;
            z[k].x = __uint_as_float(__float_as_uint(a) ^ sa);
            z[k].y = __uint_as_float(__float_as_uint(b) ^ sb);
        }
    }

    // ---- forward FFT (wave-private; scratch aliases own plane) ----
    fft512<0>(z, Mt, TAt, TBt, lane, h, w);

#pragma unroll
    for (int k = 0; k < 8; ++k) Mt[64 * k + lane] = z[k];    // spectra, natural
    __syncthreads();

    // ---- spectral einsum, in place (thread f owns slots {f, 512-f}) ----
    for (int f = tid; f <= 256; f += 256) {     // thread 0 also does f=256
        const int fm = (512 - f) & 511;
        float2 Xf[8];
#pragma unroll
        for (int c = 0; c < 4; ++c) {
            const float2 zp = LB[c * 512 + f];
            const float2 zm = LB[c * 512 + fm];
            Xf[2 * c]     = make_float2(0.5f * (zp.x + zm.x), 0.5f * (zp.y - zm.y));
            Xf[2 * c + 1] = make_float2(0.5f * (zp.y + zm.y), -0.5f * (zp.x - zm.x));
        }
        const float4* wf = Wf4 + f;
        float2 Y[8];
#pragma unroll
        for (int o = 0; o < 8; ++o) {
            float re = 0.f, im = 0.f;
#pragma unroll
            for (int i2 = 0; i2 < 4; ++i2) {
                const float4 wv = wf[(o * 4 + i2) * 257];    // coalesced dwordx4
                const float2 x0 = Xf[2 * i2], x1 = Xf[2 * i2 + 1];
                re += x0.x * wv.x - x0.y * wv.y;
                re += x1.x * wv.z - x1.y * wv.w;
                im += x0.x * wv.y + x0.y * wv.x;
                im += x1.x * wv.w + x1.y * wv.z;
            }
            Y[o] = make_float2(re, im);
        }
#pragma unroll
        for (int c = 0; c < 4; ++c) {
            const float2 y0 = Y[2 * c], y1 = Y[2 * c + 1];
            LB[c * 512 + f] = make_float2(y0.x - y1.y, y0.y + y1.x);
            if (f != 0 && f != 256)
                LB[c * 512 + 512 - f] = make_float2(y0.x + y1.y, y1.x - y0.y);
        }
    }
    __syncthreads();

    // ---- inverse FFT (reads own plane, then scratch clobbers it) ----
#pragma unroll
    for (int k = 0; k < 8; ++k) z[k] = Mt[64 * k + lane];

    fft512<1>(z, Mt, TAt, TBt, lane, h, w);

    // ---- epilogue: bias + GELU (A&S erf), coalesced stores ----
    {
        const float* bre = bias + (2 * wave) * 512;
        const float* bim = bias + (2 * wave + 1) * 512;
        float* yre = yout + (2 * wave) * 512;
        float* yim = yout + (2 * wave + 1) * 512;
#pragma unroll
        for (int k = 0; k < 8; ++k) {
            const int p = 64 * k + lane;
            yre[p] = gelu_f(z[k].x + bre[p]);
            yim[p] = gelu_f(z[k].y + bim[p]);
        }
    }
}

extern "C" void kernel_launch(void* const* d_in, const int* in_sizes, int n_in,
                              void* d_out, int out_size, void* d_ws, size_t ws_size,
                              hipStream_t stream) {
    const float* x        = (const float*)d_in[0];   // [B,S,F_IN] fp32
    const float* w        = (const float*)d_in[1];   // [QOUT,QIN,P] fp32
    const float* bias     = (const float*)d_in[2];   // [F_OUT] fp32
    const int*  sign_bits = (const int*)d_in[3];     // [F_IN] int32
    float* out = (float*)d_out;                      // [B,S,F_OUT] fp32

    float4* Wf4 = (float4*)d_ws;                     // [32][257] float4 = 131.6 KB

    wf_build<<<QOUT * QIN, 256, 0, stream>>>(w, Wf4);
    fft_conv<<<NTOK, 256, 0, stream>>>(x, sign_bits, Wf4, bias, out);
}

// Round 4
// 310.821 us; speedup vs baseline: 1.5115x; 1.1908x over previous
//
#include <hip/hip_runtime.h>
#include <stdint.h>
#include <math.h>

// Problem constants
#define NTOK 8192   // B*S tokens
#define FIN  4096
#define FOUT 4096
#define PP   512
#define QIN  8
#define QOUT 8
#define NFREQ 257   // P/2+1

// ---------------------------------------------------------------------------
// complex helpers
// ---------------------------------------------------------------------------
__device__ __forceinline__ float2 cadd(float2 a, float2 b) { return make_float2(a.x + b.x, a.y + b.y); }
__device__ __forceinline__ float2 csub(float2 a, float2 b) { return make_float2(a.x - b.x, a.y - b.y); }

// a * t, conjugating t when INV (t = forward twiddle, W = e^{-2pi i/512})
template<int INV>
__device__ __forceinline__ float2 twmul(float2 a, float2 t) {
    const float ty = INV ? -t.y : t.y;
    return make_float2(a.x * t.x - a.y * ty, a.x * ty + a.y * t.x);
}

// ---------------------------------------------------------------------------
// In-register 8-point DFT over the register index.
// ---------------------------------------------------------------------------
template<int INV>
__device__ __forceinline__ void dft8(float2 z[8]) {
    const float S = 0.70710678118654752f;
    float2 a0 = cadd(z[0], z[4]), a4 = csub(z[0], z[4]);
    float2 a1 = cadd(z[1], z[5]), a5 = csub(z[1], z[5]);
    float2 a2 = cadd(z[2], z[6]), a6 = csub(z[2], z[6]);
    float2 a3 = cadd(z[3], z[7]), a7 = csub(z[3], z[7]);
    float2 b0 = cadd(a0, a2), b2 = csub(a0, a2);
    float2 b1 = cadd(a1, a3), b3 = csub(a1, a3);
    z[0] = cadd(b0, b1);
    z[4] = csub(b0, b1);
    float2 r3 = INV ? make_float2(-b3.y, b3.x) : make_float2(b3.y, -b3.x);
    z[2] = cadd(b2, r3);
    z[6] = csub(b2, r3);
    float2 c0 = a4;
    float2 c1 = INV ? make_float2(S * (a5.x - a5.y), S * (a5.x + a5.y))
                    : make_float2(S * (a5.x + a5.y), S * (a5.y - a5.x));
    float2 c2 = INV ? make_float2(-a6.y, a6.x) : make_float2(a6.y, -a6.x);
    float2 c3 = INV ? make_float2(-S * (a7.x + a7.y), S * (a7.x - a7.y))
                    : make_float2(S * (a7.y - a7.x), -S * (a7.x + a7.y));
    float2 d0 = cadd(c0, c2), d2 = csub(c0, c2);
    float2 d1 = cadd(c1, c3), d3 = csub(c1, c3);
    z[1] = cadd(d0, d1);
    z[5] = csub(d0, d1);
    float2 r7 = INV ? make_float2(-d3.y, d3.x) : make_float2(d3.y, -d3.x);
    z[3] = cadd(d2, r7);
    z[7] = csub(d2, r7);
}

// XOR-swizzled transpose-scratch address: logical (row, col) in an 8x64 tile
// packed into 512 float2 slots.  Bijective; all four access patterns below
// land 4 lanes per bank-pair (b64 wave minimum = conflict-free).
#define SW(row, col) (((row) << 6) + ((col) ^ (((row) & 3) << 2)))

// ---------------------------------------------------------------------------
// Per-wave 512-point FFT, four-step radix-8^3 (natural order in / out).
//   n = 64*n2 + 8*n1 + n0 ; k = k0 + 8*k1 + 64*k2 ; lane = 8h + w
// TAt[k*64+lane] = W512^{8*h*k} ; TBt[k*64+lane] = W512^{(w*(h+8k))&511}
// Mt = this wave's 512-slot plane (aliases spectra storage; same-wave DS
// ordering makes the aliasing safe).
// ---------------------------------------------------------------------------
template<int INV>
__device__ __forceinline__ void fft512(float2 z[8], float2* Mt,
                                       const float2* TAt, const float2* TBt,
                                       const int lane, const int h, const int w) {
    dft8<INV>(z);                                   // over n2 -> k0
#pragma unroll
    for (int k = 1; k < 8; ++k)
        z[k] = twmul<INV>(z[k], TAt[k * 64 + lane]);
#pragma unroll
    for (int k = 0; k < 8; ++k) Mt[SW(k, lane)] = z[k];          // T1 write
#pragma unroll
    for (int k = 0; k < 8; ++k) z[k] = Mt[SW(h, 8 * k + w)];     // T1 read
    dft8<INV>(z);                                   // over n1 -> k1
#pragma unroll
    for (int k = 0; k < 8; ++k)
        z[k] = twmul<INV>(z[k], TBt[k * 64 + lane]);
#pragma unroll
    for (int k = 0; k < 8; ++k) Mt[SW(k, 8 * w + h)] = z[k];     // T2 write
#pragma unroll
    for (int k = 0; k < 8; ++k) z[k] = Mt[SW(h, 8 * k + w)];     // T2 read
    dft8<INV>(z);                                   // over n0 -> k2
}

// ---------------------------------------------------------------------------
// Cheap exact-enough GELU: A&S 7.1.26 erf (|eps| <= 1.5e-7), rcp + exp + 5 fma.
// ---------------------------------------------------------------------------
__device__ __forceinline__ float gelu_f(float v) {
    const float a = fabsf(v) * 0.70710678118654752f;
    const float t = __builtin_amdgcn_rcpf(fmaf(0.3275911f, a, 1.0f));
    float p = fmaf(1.061405429f, t, -1.453152027f);
    p = fmaf(p, t, 1.421413741f);
    p = fmaf(p, t, -0.284496736f);
    p = fmaf(p, t, 0.254829592f);
    p = p * t;
    const float e = __expf(-a * a);
    float erfa = fmaf(-p, e, 1.0f);         // erf(|v|/sqrt2)
    erfa = copysignf(erfa, v);
    return 0.5f * v * (1.0f + erfa);
}

// ---------------------------------------------------------------------------
// wf_build: Wf4[(o*4+i2)*257 + f] = float4{ Wf[o][2*i2][f], Wf[o][2*i2+1][f] }
// (pairs of adjacent input blocks packed so fft_conv loads dwordx4).
// Wf = (1/512) * rfft(w[o][i]).  Block blk = o*8+i computes one (o,i) row
// and writes its float2 half-slot.  libm sincos kept here (64 blocks only).
// ---------------------------------------------------------------------------
__global__ __launch_bounds__(256) void wf_build(const float* __restrict__ w,
                                                float4* __restrict__ Wf4) {
    __shared__ float  sw[512];
    __shared__ float2 tb[512];          // tb[k] = W^k = (cos, -sin)(2pi k/512)
    __shared__ float2 red[4][64];
    const int blk = blockIdx.x;         // o*8 + i
    const float* wrow = w + (size_t)blk * 512;
    const int t   = threadIdx.x;
    const int fi  = t & 63;
    const int seg = t >> 6;
    sw[t]       = wrow[t];
    sw[t + 256] = wrow[t + 256];
    const float th = -6.283185307179586f / 512.0f;
    {
        float a0 = th * (float)t, a1 = th * (float)(t + 256);
        tb[t]       = make_float2(cosf(a0), sinf(a0));
        tb[t + 256] = make_float2(cosf(a1), sinf(a1));
    }
    __syncthreads();
    const int o = blk >> 3, i = blk & 7;
    float2* dst_base = (float2*)Wf4 + (i & 1);      // float4 slot = 2 float2
    for (int g = 0; g < 5; ++g) {
        const int f = (g < 4) ? (g * 64 + fi) : 256;
        float re = 0.f, im = 0.f;
        int idx = (f * (seg * 128)) & 511;
        for (int n = 0; n < 128; ++n) {
            const float2 e = tb[idx];
            const float  v = sw[seg * 128 + n];
            re += v * e.x;
            im += v * e.y;
            idx = (idx + f) & 511;
        }
        red[seg][fi] = make_float2(re, im);
        __syncthreads();
        if (seg == 0) {
            float2 r0 = red[0][fi], r1 = red[1][fi], r2 = red[2][fi], r3 = red[3][fi];
            float rre = (r0.x + r1.x) + (r2.x + r3.x);
            float rim = (r0.y + r1.y) + (r2.y + r3.y);
            if (g < 4 || fi == 0)
                dst_base[((size_t)(o * 4 + (i >> 1)) * 257 + f) * 2] =
                    make_float2(rre * (1.f / 512.f), rim * (1.f / 512.f));
        }
        __syncthreads();
    }
}

// ---------------------------------------------------------------------------
// fft_conv: one block (256 thr, 4 waves) per token.  Wave c handles packed
// complex sequence Z_c = xs[2c] + i*xs[2c+1].
// LDS (float2 units), 3072 total = 24576 B:
//   ZS  [0,2048)     : c*512 + n  — spectra; ALSO per-wave fft512 scratch and
//                      einsum output (in-place: slot s is read AND written by
//                      exactly one thread -> race-free across waves)
//   TAt [2048,2560)  : k*64+lane twiddles, stage A
//   TBt [2560,3072)  : k*64+lane twiddles, stage B
// NOTE on __launch_bounds__: on this toolchain the 2nd arg w caps VGPRs at
// 256/w — (256,5) gave 48 VGPR, (256,4) gave 64 VGPR, both spilled hundreds
// of MB to scratch (R2/R3 FETCH/WRITE counters).  No 2nd arg -> allocator
// picks ~88 VGPR, zero spill (R1).  LDS (6 blocks/CU) is the occupancy cap.
// ---------------------------------------------------------------------------
__global__ __launch_bounds__(256) void fft_conv(const float* __restrict__ x,
                                                const int* __restrict__ sign_bits,
                                                const float4* __restrict__ Wf4,
                                                const float* __restrict__ bias,
                                                float* __restrict__ out) {
    __shared__ float2 LB[3072];

    const int tid  = threadIdx.x;
    const int wave = tid >> 6;
    const int lane = tid & 63;
    const int h = lane >> 3, w = lane & 7;
    const float* xin  = x   + (size_t)blockIdx.x * FIN;
    float*       yout = out + (size_t)blockIdx.x * FOUT;

    // ---- per-lane twiddle tables (HW sincos, no libm, no per-stage idx math)
    for (int j = tid; j < 1024; j += 256) {
        const int k  = (j >> 6) & 7;
        const int l  = j & 63;
        const int hh = l >> 3, ww = l & 7;
        const int e  = (j < 512) ? ((8 * hh * k) & 511)
                                 : ((ww * (hh + 8 * k)) & 511);
        float sn, cs;
        __sincosf((-6.283185307179586f / 512.0f) * (float)e, &sn, &cs);
        LB[2048 + j] = make_float2(cs, sn);
    }
    __syncthreads();

    const float2* TAt = &LB[2048];
    const float2* TBt = &LB[2560];
    float2* Mt = &LB[wave * 512];        // wave-private plane (scratch+spectra)

    // ---- pack x*sign into registers (reg k = element 64k+lane) ----
    float2 z[8];
    {
        const float* xre = xin + (2 * wave) * 512;
        const float* xim = xin + (2 * wave + 1) * 512;
        const int*   sre = sign_bits + (2 * wave) * 512;
        const int*   sim = sign_bits + (2 * wave + 1) * 512;
#pragma unroll
        for (int k = 0; k < 8; ++k) {
            const int p = 64 * k + lane;
            float a = xre[p], b = xim[p];
            unsigned sa = (unsigned)sre[p] << 31;
            unsigned sb = (unsigned)sim[p] << 31;
            z[k].x = __uint_as_float(__float_as_uint(a) ^ sa);
            z[k].y = __uint_as_float(__float_as_uint(b) ^ sb);
        }
    }

    // ---- forward FFT (wave-private; scratch aliases own plane) ----
    fft512<0>(z, Mt, TAt, TBt, lane, h, w);

#pragma unroll
    for (int k = 0; k < 8; ++k) Mt[64 * k + lane] = z[k];    // spectra, natural
    __syncthreads();

    // ---- spectral einsum, in place (thread f owns slots {f, 512-f}) ----
    for (int f = tid; f <= 256; f += 256) {     // thread 0 also does f=256
        const int fm = (512 - f) & 511;
        float2 Xf[8];
#pragma unroll
        for (int c = 0; c < 4; ++c) {
            const float2 zp = LB[c * 512 + f];
            const float2 zm = LB[c * 512 + fm];
            Xf[2 * c]     = make_float2(0.5f * (zp.x + zm.x), 0.5f * (zp.y - zm.y));
            Xf[2 * c + 1] = make_float2(0.5f * (zp.y + zm.y), -0.5f * (zp.x - zm.x));
        }
        const float4* wf = Wf4 + f;
        float2 Y[8];
#pragma unroll
        for (int o = 0; o < 8; ++o) {
            float re = 0.f, im = 0.f;
#pragma unroll
            for (int i2 = 0; i2 < 4; ++i2) {
                const float4 wv = wf[(o * 4 + i2) * 257];    // coalesced dwordx4
                const float2 x0 = Xf[2 * i2], x1 = Xf[2 * i2 + 1];
                re += x0.x * wv.x - x0.y * wv.y;
                re += x1.x * wv.z - x1.y * wv.w;
                im += x0.x * wv.y + x0.y * wv.x;
                im += x1.x * wv.w + x1.y * wv.z;
            }
            Y[o] = make_float2(re, im);
        }
#pragma unroll
        for (int c = 0; c < 4; ++c) {
            const float2 y0 = Y[2 * c], y1 = Y[2 * c + 1];
            LB[c * 512 + f] = make_float2(y0.x - y1.y, y0.y + y1.x);
            if (f != 0 && f != 256)
                LB[c * 512 + 512 - f] = make_float2(y0.x + y1.y, y1.x - y0.y);
        }
    }
    __syncthreads();

    // ---- inverse FFT (reads own plane, then scratch clobbers it) ----
#pragma unroll
    for (int k = 0; k < 8; ++k) z[k] = Mt[64 * k + lane];

    fft512<1>(z, Mt, TAt, TBt, lane, h, w);

    // ---- epilogue: bias + GELU (A&S erf), coalesced stores ----
    {
        const float* bre = bias + (2 * wave) * 512;
        const float* bim = bias + (2 * wave + 1) * 512;
        float* yre = yout + (2 * wave) * 512;
        float* yim = yout + (2 * wave + 1) * 512;
#pragma unroll
        for (int k = 0; k < 8; ++k) {
            const int p = 64 * k + lane;
            yre[p] = gelu_f(z[k].x + bre[p]);
            yim[p] = gelu_f(z[k].y + bim[p]);
        }
    }
}

extern "C" void kernel_launch(void* const* d_in, const int* in_sizes, int n_in,
                              void* d_out, int out_size, void* d_ws, size_t ws_size,
                              hipStream_t stream) {
    const float* x        = (const float*)d_in[0];   // [B,S,F_IN] fp32
    const float* w        = (const float*)d_in[1];   // [QOUT,QIN,P] fp32
    const float* bias     = (const float*)d_in[2];   // [F_OUT] fp32
    const int*  sign_bits = (const int*)d_in[3];     // [F_IN] int32
    float* out = (float*)d_out;                      // [B,S,F_OUT] fp32

    float4* Wf4 = (float4*)d_ws;                     // [32][257] float4 = 131.6 KB

    wf_build<<<QOUT * QIN, 256, 0, stream>>>(w, Wf4);
    fft_conv<<<NTOK, 256, 0, stream>>>(x, sign_bits, Wf4, bias, out);
}

// Round 5
// 294.465 us; speedup vs baseline: 1.5954x; 1.0555x over previous
//
#include <hip/hip_runtime.h>
#include <stdint.h>
#include <math.h>

// Problem constants
#define NTOK 8192   // B*S tokens
#define FIN  4096
#define FOUT 4096
#define PP   512
#define QIN  8
#define QOUT 8
#define NFREQ 257   // P/2+1

// ---------------------------------------------------------------------------
// complex helpers
// ---------------------------------------------------------------------------
__device__ __forceinline__ float2 cadd(float2 a, float2 b) { return make_float2(a.x + b.x, a.y + b.y); }
__device__ __forceinline__ float2 csub(float2 a, float2 b) { return make_float2(a.x - b.x, a.y - b.y); }

// a * t, conjugating t when INV (t = forward twiddle, W = e^{-2pi i/512})
template<int INV>
__device__ __forceinline__ float2 twmul(float2 a, float2 t) {
    const float ty = INV ? -t.y : t.y;
    return make_float2(a.x * t.x - a.y * ty, a.x * ty + a.y * t.x);
}

// ---------------------------------------------------------------------------
// In-register 8-point DFT over the register index.
// ---------------------------------------------------------------------------
template<int INV>
__device__ __forceinline__ void dft8(float2 z[8]) {
    const float S = 0.70710678118654752f;
    float2 a0 = cadd(z[0], z[4]), a4 = csub(z[0], z[4]);
    float2 a1 = cadd(z[1], z[5]), a5 = csub(z[1], z[5]);
    float2 a2 = cadd(z[2], z[6]), a6 = csub(z[2], z[6]);
    float2 a3 = cadd(z[3], z[7]), a7 = csub(z[3], z[7]);
    float2 b0 = cadd(a0, a2), b2 = csub(a0, a2);
    float2 b1 = cadd(a1, a3), b3 = csub(a1, a3);
    z[0] = cadd(b0, b1);
    z[4] = csub(b0, b1);
    float2 r3 = INV ? make_float2(-b3.y, b3.x) : make_float2(b3.y, -b3.x);
    z[2] = cadd(b2, r3);
    z[6] = csub(b2, r3);
    float2 c0 = a4;
    float2 c1 = INV ? make_float2(S * (a5.x - a5.y), S * (a5.x + a5.y))
                    : make_float2(S * (a5.x + a5.y), S * (a5.y - a5.x));
    float2 c2 = INV ? make_float2(-a6.y, a6.x) : make_float2(a6.y, -a6.x);
    float2 c3 = INV ? make_float2(-S * (a7.x + a7.y), S * (a7.x - a7.y))
                    : make_float2(S * (a7.y - a7.x), -S * (a7.x + a7.y));
    float2 d0 = cadd(c0, c2), d2 = csub(c0, c2);
    float2 d1 = cadd(c1, c3), d3 = csub(c1, c3);
    z[1] = cadd(d0, d1);
    z[5] = csub(d0, d1);
    float2 r7 = INV ? make_float2(-d3.y, d3.x) : make_float2(d3.y, -d3.x);
    z[3] = cadd(d2, r7);
    z[7] = csub(d2, r7);
}

// ---------------------------------------------------------------------------
// Per-wave 512-point FFT, four-step radix-8^3 (natural order in / out).
//   n = 64*n2 + 8*n1 + n0 ; k = k0 + 8*k1 + 64*k2 ; lane = 8h + w
// Scratch plane: 8 logical rows x 64 cols stored at stride 68 (PADDED rows —
// replaces the R4 XOR swizzle).  Every DS access is base + compile-time
// immediate (544k / 64k bytes), so zero per-op VALU address math.  Bank
// check (addr mod 16) for each pattern:
//   T1 write  lane + 68k      -> (lane+4k) mod 16        : 4 lanes/pair
//   T1/T2 rd  68h + w + 8k    -> (4(h&3)+w+8k) mod 16    : 4 lanes/pair
//   T2 write  8w + h + 68k    -> (8(w&1)+h+4k) mod 16    : 4 lanes/pair
// all at the wave64-b64 structural floor = conflict-free.
// TA64[h*8+k] = W64^{h*k} (broadcast: 8 lanes/address, 4 addrs/pair).
// TBt[k*64+lane] = W512^{(w*(h+8k))&511}.
// Same-wave DS ops are processed in order -> no barriers inside.
// ---------------------------------------------------------------------------
template<int INV>
__device__ __forceinline__ void fft512(float2 z[8], float2* plane,
                                       const float2* TA64, const float2* TBt,
                                       const int lane, const int h, const int w,
                                       const int bRd, const int bW2) {
    dft8<INV>(z);                                   // over n2 -> k0
#pragma unroll
    for (int k = 1; k < 8; ++k)
        z[k] = twmul<INV>(z[k], TA64[h * 8 + k]);
#pragma unroll
    for (int k = 0; k < 8; ++k) plane[68 * k + lane] = z[k];     // T1 write
#pragma unroll
    for (int k = 0; k < 8; ++k) z[k] = plane[bRd + 8 * k];       // T1 read
    dft8<INV>(z);                                   // over n1 -> k1
#pragma unroll
    for (int k = 0; k < 8; ++k)
        z[k] = twmul<INV>(z[k], TBt[k * 64 + lane]);
#pragma unroll
    for (int k = 0; k < 8; ++k) plane[68 * k + bW2] = z[k];      // T2 write
#pragma unroll
    for (int k = 0; k < 8; ++k) z[k] = plane[bRd + 8 * k];       // T2 read
    dft8<INV>(z);                                   // over n0 -> k2
}

// ---------------------------------------------------------------------------
// Cheap exact-enough GELU: A&S 7.1.26 erf (|eps| <= 1.5e-7), rcp + exp + 5 fma.
// ---------------------------------------------------------------------------
__device__ __forceinline__ float gelu_f(float v) {
    const float a = fabsf(v) * 0.70710678118654752f;
    const float t = __builtin_amdgcn_rcpf(fmaf(0.3275911f, a, 1.0f));
    float p = fmaf(1.061405429f, t, -1.453152027f);
    p = fmaf(p, t, 1.421413741f);
    p = fmaf(p, t, -0.284496736f);
    p = fmaf(p, t, 0.254829592f);
    p = p * t;
    const float e = __expf(-a * a);
    float erfa = fmaf(-p, e, 1.0f);         // erf(|v|/sqrt2)
    erfa = copysignf(erfa, v);
    return 0.5f * v * (1.0f + erfa);
}

// ---------------------------------------------------------------------------
// wf_build: Wf4[(o*4+i2)*257 + f] = float4{ Wf[o][2*i2][f], Wf[o][2*i2+1][f] }
// Scale = 1/1024: 1/512 (irfft norm) x 1/2 (Hermitian-unpack halves folded
// out of fft_conv's einsum).
// ---------------------------------------------------------------------------
__global__ __launch_bounds__(256) void wf_build(const float* __restrict__ w,
                                                float4* __restrict__ Wf4) {
    __shared__ float  sw[512];
    __shared__ float2 tb[512];          // tb[k] = W^k = (cos, -sin)(2pi k/512)
    __shared__ float2 red[4][64];
    const int blk = blockIdx.x;         // o*8 + i
    const float* wrow = w + (size_t)blk * 512;
    const int t   = threadIdx.x;
    const int fi  = t & 63;
    const int seg = t >> 6;
    sw[t]       = wrow[t];
    sw[t + 256] = wrow[t + 256];
    const float th = -6.283185307179586f / 512.0f;
    {
        float a0 = th * (float)t, a1 = th * (float)(t + 256);
        tb[t]       = make_float2(cosf(a0), sinf(a0));
        tb[t + 256] = make_float2(cosf(a1), sinf(a1));
    }
    __syncthreads();
    const int o = blk >> 3, i = blk & 7;
    float2* dst_base = (float2*)Wf4 + (i & 1);      // float4 slot = 2 float2
    for (int g = 0; g < 5; ++g) {
        const int f = (g < 4) ? (g * 64 + fi) : 256;
        float re = 0.f, im = 0.f;
        int idx = (f * (seg * 128)) & 511;
        for (int n = 0; n < 128; ++n) {
            const float2 e = tb[idx];
            const float  v = sw[seg * 128 + n];
            re += v * e.x;
            im += v * e.y;
            idx = (idx + f) & 511;
        }
        red[seg][fi] = make_float2(re, im);
        __syncthreads();
        if (seg == 0) {
            float2 r0 = red[0][fi], r1 = red[1][fi], r2 = red[2][fi], r3 = red[3][fi];
            float rre = (r0.x + r1.x) + (r2.x + r3.x);
            float rim = (r0.y + r1.y) + (r2.y + r3.y);
            if (g < 4 || fi == 0)
                dst_base[((size_t)(o * 4 + (i >> 1)) * 257 + f) * 2] =
                    make_float2(rre * (1.f / 1024.f), rim * (1.f / 1024.f));
        }
        __syncthreads();
    }
}

// ---------------------------------------------------------------------------
// fft_conv: one block (256 thr, 4 waves) per token.  Wave c handles packed
// complex sequence Z_c = xs[2c] + i*xs[2c+1].
// LDS (float2 units), 2752 total = 22016 B:
//   planes [0,2176)    : wave*544 — padded-68 FFT scratch; slots [0,512) also
//                        hold spectra (natural n) and einsum output (in-place:
//                        slot pair {f,512-f} owned by exactly one thread)
//   TA64  [2176,2240)  : h*8+k -> W64^{hk}
//   TBt   [2240,2752)  : k*64+lane -> W512^{(w*(h+8k))&511}
// NOTE __launch_bounds__: 2nd arg w caps VGPRs at 256/w on this toolchain
// ((256,5)->48, (256,4)->64, both spilled hundreds of MB — R2/R3).  No 2nd
// arg -> ~84 VGPR, zero spill.
// ---------------------------------------------------------------------------
__global__ __launch_bounds__(256) void fft_conv(const float* __restrict__ x,
                                                const int* __restrict__ sign_bits,
                                                const float4* __restrict__ Wf4,
                                                const float* __restrict__ bias,
                                                float* __restrict__ out) {
    __shared__ float2 LB[2752];

    const int tid  = threadIdx.x;
    const int wave = tid >> 6;
    const int lane = tid & 63;
    const int h = lane >> 3, w = lane & 7;
    const int bRd = 68 * h + w;          // fft512 transpose-read base
    const int bW2 = 8 * w + h;           // fft512 T2-write col base
    const float* xin  = x   + (size_t)blockIdx.x * FIN;
    float*       yout = out + (size_t)blockIdx.x * FOUT;

    // ---- twiddle tables (HW sincos) ----
    {
        const float th = -6.283185307179586f / 512.0f;
        if (tid < 64) {                  // TA64[h*8+k] = W64^{hk} = W512^{8hk}
            const int hh = tid >> 3, kk = tid & 7;
            float sn, cs;
            __sincosf(th * (float)(8 * hh * kk), &sn, &cs);
            LB[2176 + tid] = make_float2(cs, sn);
        }
        for (int j = tid; j < 512; j += 256) {   // TBt
            const int k = j >> 6, l = j & 63;
            const int e = ((l & 7) * ((l >> 3) + 8 * k)) & 511;
            float sn, cs;
            __sincosf(th * (float)e, &sn, &cs);
            LB[2240 + j] = make_float2(cs, sn);
        }
    }
    __syncthreads();

    const float2* TA64 = &LB[2176];
    const float2* TBt  = &LB[2240];
    float2* plane = &LB[wave * 544];     // wave-private scratch + spectra

    // ---- pack x*sign into registers (reg k = element 64k+lane) ----
    float2 z[8];
    {
        const float* xre = xin + (2 * wave) * 512;
        const float* xim = xin + (2 * wave + 1) * 512;
        const int*   sre = sign_bits + (2 * wave) * 512;
        const int*   sim = sign_bits + (2 * wave + 1) * 512;
#pragma unroll
        for (int k = 0; k < 8; ++k) {
            const int p = 64 * k + lane;
            float a = xre[p], b = xim[p];
            unsigned sa = (unsigned)sre[p] << 31;
            unsigned sb = (unsigned)sim[p] << 31;
            z[k].x = __uint_as_float(__float_as_uint(a) ^ sa);
            z[k].y = __uint_as_float(__float_as_uint(b) ^ sb);
        }
    }

    // ---- forward FFT (wave-private) ----
    fft512<0>(z, plane, TA64, TBt, lane, h, w, bRd, bW2);

#pragma unroll
    for (int k = 0; k < 8; ++k) plane[64 * k + lane] = z[k];     // spectra
    __syncthreads();

    // ---- spectral einsum, in place (thread f owns slots {f, 512-f}) ----
    for (int f = tid; f <= 256; f += 256) {     // thread 0 also does f=256
        const int fm = (512 - f) & 511;
        float2 Xf[8];
#pragma unroll
        for (int c = 0; c < 4; ++c) {
            const float2 zp = LB[c * 544 + f];
            const float2 zm = LB[c * 544 + fm];
            // halves folded into Wf4 (wf_build scale 1/1024)
            Xf[2 * c]     = make_float2(zp.x + zm.x, zp.y - zm.y);
            Xf[2 * c + 1] = make_float2(zp.y + zm.y, zm.x - zp.x);
        }
        const float4* wf = Wf4 + f;
        float2 Y[8];
#pragma unroll
        for (int o = 0; o < 8; ++o) {
            float re = 0.f, im = 0.f;
#pragma unroll
            for (int i2 = 0; i2 < 4; ++i2) {
                const float4 wv = wf[(o * 4 + i2) * 257];    // coalesced dwordx4
                const float2 x0 = Xf[2 * i2], x1 = Xf[2 * i2 + 1];
                re += x0.x * wv.x - x0.y * wv.y;
                re += x1.x * wv.z - x1.y * wv.w;
                im += x0.x * wv.y + x0.y * wv.x;
                im += x1.x * wv.w + x1.y * wv.z;
            }
            Y[o] = make_float2(re, im);
        }
#pragma unroll
        for (int c = 0; c < 4; ++c) {
            const float2 y0 = Y[2 * c], y1 = Y[2 * c + 1];
            LB[c * 544 + f] = make_float2(y0.x - y1.y, y0.y + y1.x);
            if (f != 0 && f != 256)
                LB[c * 544 + 512 - f] = make_float2(y0.x + y1.y, y1.x - y0.y);
        }
    }
    __syncthreads();

    // ---- inverse FFT (reads own plane, then scratch clobbers it) ----
#pragma unroll
    for (int k = 0; k < 8; ++k) z[k] = plane[64 * k + lane];

    fft512<1>(z, plane, TA64, TBt, lane, h, w, bRd, bW2);

    // ---- epilogue: bias + GELU (A&S erf), coalesced stores ----
    {
        const float* bre = bias + (2 * wave) * 512;
        const float* bim = bias + (2 * wave + 1) * 512;
        float* yre = yout + (2 * wave) * 512;
        float* yim = yout + (2 * wave + 1) * 512;
#pragma unroll
        for (int k = 0; k < 8; ++k) {
            const int p = 64 * k + lane;
            yre[p] = gelu_f(z[k].x + bre[p]);
            yim[p] = gelu_f(z[k].y + bim[p]);
        }
    }
}

extern "C" void kernel_launch(void* const* d_in, const int* in_sizes, int n_in,
                              void* d_out, int out_size, void* d_ws, size_t ws_size,
                              hipStream_t stream) {
    const float* x        = (const float*)d_in[0];   // [B,S,F_IN] fp32
    const float* w        = (const float*)d_in[1];   // [QOUT,QIN,P] fp32
    const float* bias     = (const float*)d_in[2];   // [F_OUT] fp32
    const int*  sign_bits = (const int*)d_in[3];     // [F_IN] int32
    float* out = (float*)d_out;                      // [B,S,F_OUT] fp32

    float4* Wf4 = (float4*)d_ws;                     // [32][257] float4 = 131.6 KB

    wf_build<<<QOUT * QIN, 256, 0, stream>>>(w, Wf4);
    fft_conv<<<NTOK, 256, 0, stream>>>(x, sign_bits, Wf4, bias, out);
}